// Round 1
// baseline (3097.211 us; speedup 1.0000x reference)
//
#include <hip/hip_runtime.h>

#define N_NODES 500000

// ---------------------------------------------------------------------------
// Kernel 1: in-degree count over real edges (self-loop added analytically)
// ---------------------------------------------------------------------------
__global__ void k_count_deg(const int* __restrict__ dst, int E,
                            unsigned int* __restrict__ deg) {
    int i = blockIdx.x * blockDim.x + threadIdx.x;
    int stride = gridDim.x * blockDim.x;
    for (int e = i; e < E; e += stride) {
        atomicAdd(&deg[dst[e]], 1u);
    }
}

// ---------------------------------------------------------------------------
// Kernel 2: dis = rsqrt(deg+1);  s seeded with self-loop term dis^2 * x
// ---------------------------------------------------------------------------
__global__ void k_dis_sinit(const unsigned int* __restrict__ deg,
                            const float* __restrict__ x,
                            float* __restrict__ dis,
                            float* __restrict__ s, int N) {
    int i = blockIdx.x * blockDim.x + threadIdx.x;
    if (i < N) {
        float d = (float)(deg[i] + 1u);   // +1: self-loop; always > 0
        float r = rsqrtf(d);
        dis[i] = r;
        s[i] = r * r * x[i];
    }
}

// ---------------------------------------------------------------------------
// Kernel 3: layer-1 scalar aggregation  s[dst] += dis[src]*dis[dst]*x[src]
// ---------------------------------------------------------------------------
__global__ void k_agg1(const int* __restrict__ src, const int* __restrict__ dst,
                       int E, const float* __restrict__ dis,
                       const float* __restrict__ x, float* __restrict__ s) {
    int i = blockIdx.x * blockDim.x + threadIdx.x;
    int stride = gridDim.x * blockDim.x;
    for (int e = i; e < E; e += stride) {
        int sj = src[e];
        int dj = dst[e];
        float v = dis[sj] * dis[dj] * x[sj];
        atomicAdd(&s[dj], v);
    }
}

// ---------------------------------------------------------------------------
// Kernel 4: per-node MLP.  h[k] = relu(W1[k]*s + b1[k]); h2 = h @ W2.
// Also writes out[i] = b2 + dis^2 * h2[i]  (bias + self-loop contribution).
// ---------------------------------------------------------------------------
__global__ void k_node2(const float* __restrict__ s,
                        const float* __restrict__ dis,
                        const float* __restrict__ W1,
                        const float* __restrict__ b1,
                        const float* __restrict__ W2,
                        const float* __restrict__ b2,
                        float2* __restrict__ h2,
                        float2* __restrict__ out, int N) {
    int i = blockIdx.x * blockDim.x + threadIdx.x;
    if (i >= N) return;
    float si = s[i];
    float a0 = 0.f, a1 = 0.f;
#pragma unroll
    for (int k = 0; k < 8; ++k) {
        float hk = fmaxf(W1[k] * si + b1[k], 0.f);
        a0 += hk * W2[2 * k + 0];
        a1 += hk * W2[2 * k + 1];
    }
    h2[i] = make_float2(a0, a1);
    float r2 = dis[i] * dis[i];
    out[i] = make_float2(b2[0] + r2 * a0, b2[1] + r2 * a1);
}

// ---------------------------------------------------------------------------
// Kernel 5: layer-2 aggregation  out[dst] += norm * h2[src]   (2 atomics/edge)
// ---------------------------------------------------------------------------
__global__ void k_agg2(const int* __restrict__ src, const int* __restrict__ dst,
                       int E, const float* __restrict__ dis,
                       const float2* __restrict__ h2, float* __restrict__ out) {
    int i = blockIdx.x * blockDim.x + threadIdx.x;
    int stride = gridDim.x * blockDim.x;
    for (int e = i; e < E; e += stride) {
        int sj = src[e];
        int dj = dst[e];
        float n = dis[sj] * dis[dj];
        float2 v = h2[sj];
        atomicAdd(&out[2 * dj + 0], n * v.x);
        atomicAdd(&out[2 * dj + 1], n * v.y);
    }
}

extern "C" void kernel_launch(void* const* d_in, const int* in_sizes, int n_in,
                              void* d_out, int out_size, void* d_ws, size_t ws_size,
                              hipStream_t stream) {
    const float* x  = (const float*)d_in[0];
    const int*   ei = (const int*)d_in[1];   // [2, E] flat: src then dst
    const float* W1 = (const float*)d_in[2];
    const float* b1 = (const float*)d_in[3];
    const float* W2 = (const float*)d_in[4];
    const float* b2 = (const float*)d_in[5];

    const int N = N_NODES;
    const int E = in_sizes[1] / 2;
    const int* src = ei;
    const int* dst = ei + E;

    // workspace layout (bytes):
    //   [0, 2MB)   deg   (uint32, N)
    //   [2, 4MB)   dis   (float, N)
    //   [4, 6MB)   s     (float, N)
    //   [6, 10MB)  h2    (float2, N)
    char* ws = (char*)d_ws;
    unsigned int* deg = (unsigned int*)(ws);
    float* dis        = (float*)(ws + (size_t)N * 4);
    float* s          = (float*)(ws + (size_t)N * 8);
    float2* h2        = (float2*)(ws + (size_t)N * 12);

    float* out = (float*)d_out;

    hipMemsetAsync(deg, 0, (size_t)N * sizeof(unsigned int), stream);

    const int TB = 256;
    int nodeBlocks = (N + TB - 1) / TB;
    int edgeBlocks = (E + TB - 1) / TB;

    k_count_deg<<<edgeBlocks, TB, 0, stream>>>(dst, E, deg);
    k_dis_sinit<<<nodeBlocks, TB, 0, stream>>>(deg, x, dis, s, N);
    k_agg1<<<edgeBlocks, TB, 0, stream>>>(src, dst, E, dis, x, s);
    k_node2<<<nodeBlocks, TB, 0, stream>>>(s, dis, W1, b1, W2, b2, h2,
                                           (float2*)out, N);
    k_agg2<<<edgeBlocks, TB, 0, stream>>>(src, dst, E, dis, h2, out);
}

// Round 2
// 794.374 us; speedup vs baseline: 3.8989x; 3.8989x over previous
//
#include <hip/hip_runtime.h>

#define N_NODES 500000
#define NPB 1024                      // nodes per bucket (dst >> 10)
#define NBUCK ((N_NODES + NPB - 1) / NPB)   // 489
#define CHUNK 65536                   // edges per binning workgroup
#define TB 256

// ===========================================================================
// Fast path: bin edges by dst bucket, then LDS-accumulate per bucket.
// ===========================================================================

// ---- P1a: per-chunk bucket histogram; reserve space via 1 atomic/(wg,bucket)
__global__ void k_bin_count(const int* __restrict__ dst, int E,
                            unsigned int* __restrict__ counts,
                            unsigned int* __restrict__ aux) {
    __shared__ unsigned int hist[NBUCK];
    int tid = threadIdx.x, bid = blockIdx.x;
    for (int b = tid; b < NBUCK; b += TB) hist[b] = 0;
    __syncthreads();
    int eend = min(E, (bid + 1) * CHUNK);
    for (int e = bid * CHUNK + tid; e < eend; e += TB) {
        atomicAdd(&hist[dst[e] >> 10], 1u);
    }
    __syncthreads();
    unsigned int* row = aux + (size_t)bid * NBUCK;
    for (int b = tid; b < NBUCK; b += TB) {
        row[b] = atomicAdd(&counts[b], hist[b]);   // old value = my base in bucket
    }
}

// ---- scan: exclusive prefix over bucket counts (single WG)
__global__ void k_scan(const unsigned int* __restrict__ counts,
                       unsigned int* __restrict__ bucket_base) {
    __shared__ unsigned int sc[512];
    int tid = threadIdx.x;
    unsigned int v = (tid < NBUCK) ? counts[tid] : 0u;
    sc[tid] = v;
    __syncthreads();
    for (int off = 1; off < 512; off <<= 1) {
        unsigned int t = (tid >= off) ? sc[tid - off] : 0u;
        __syncthreads();
        sc[tid] += t;
        __syncthreads();
    }
    if (tid <= NBUCK) bucket_base[tid] = sc[tid] - v;  // exclusive; [NBUCK]=total
}

// ---- P1b: scatter packed records (dstlocal<<22 | src) into bucket regions
__global__ void k_bin_scatter(const int* __restrict__ src,
                              const int* __restrict__ dst, int E,
                              const unsigned int* __restrict__ bucket_base,
                              const unsigned int* __restrict__ aux,
                              unsigned int* __restrict__ rec) {
    __shared__ unsigned int cur[NBUCK];
    int tid = threadIdx.x, bid = blockIdx.x;
    const unsigned int* row = aux + (size_t)bid * NBUCK;
    for (int b = tid; b < NBUCK; b += TB) cur[b] = bucket_base[b] + row[b];
    __syncthreads();
    int eend = min(E, (bid + 1) * CHUNK);
    for (int e = bid * CHUNK + tid; e < eend; e += TB) {
        int d = dst[e];
        int s = src[e];
        int b = d >> 10;
        unsigned int pos = atomicAdd(&cur[b], 1u);
        rec[pos] = ((unsigned int)(d & (NPB - 1)) << 22) | (unsigned int)s;
    }
}

// ---- P2: per-bucket degree count -> dis = rsqrt(deg+1), m1 = dis*x
__global__ void k_deg_dis(const unsigned int* __restrict__ rec,
                          const unsigned int* __restrict__ bucket_base,
                          const float* __restrict__ x,
                          float* __restrict__ dis, float* __restrict__ m1) {
    __shared__ unsigned int cnt[NPB];
    int tid = threadIdx.x, bid = blockIdx.x;
    for (int l = tid; l < NPB; l += TB) cnt[l] = 0;
    __syncthreads();
    unsigned int e0 = bucket_base[bid], e1 = bucket_base[bid + 1];
    for (unsigned int e = e0 + tid; e < e1; e += TB) {
        atomicAdd(&cnt[rec[e] >> 22], 1u);
    }
    __syncthreads();
    int node0 = bid << 10;
    int nn = min(NPB, N_NODES - node0);
    for (int l = tid; l < nn; l += TB) {
        int node = node0 + l;
        float r = rsqrtf((float)(cnt[l] + 1u));   // +1 self-loop; always > 0
        dis[node] = r;
        m1[node] = r * x[node];
    }
}

// ---- P3: layer-1 LDS aggregation + node MLP; writes h2m and out(self+bias)
__global__ void k_layer1(const unsigned int* __restrict__ rec,
                         const unsigned int* __restrict__ bucket_base,
                         const float* __restrict__ dis,
                         const float* __restrict__ m1,
                         const float* __restrict__ W1,
                         const float* __restrict__ b1,
                         const float* __restrict__ W2,
                         const float* __restrict__ b2,
                         float2* __restrict__ h2m,
                         float2* __restrict__ out) {
    __shared__ float acc[NPB];
    int tid = threadIdx.x, bid = blockIdx.x;
    for (int l = tid; l < NPB; l += TB) acc[l] = 0.f;
    __syncthreads();
    unsigned int e0 = bucket_base[bid], e1 = bucket_base[bid + 1];
    for (unsigned int e = e0 + tid; e < e1; e += TB) {
        unsigned int r = rec[e];
        atomicAdd(&acc[r >> 22], m1[r & 0x3FFFFFu]);
    }
    __syncthreads();
    int node0 = bid << 10;
    int nn = min(NPB, N_NODES - node0);
    float w1[8], bb1[8], w2[16];
    float bb20 = b2[0], bb21 = b2[1];
#pragma unroll
    for (int k = 0; k < 8; ++k) { w1[k] = W1[k]; bb1[k] = b1[k]; }
#pragma unroll
    for (int k = 0; k < 16; ++k) w2[k] = W2[k];
    for (int l = tid; l < nn; l += TB) {
        int node = node0 + l;
        float d = dis[node];
        float s = d * (acc[l] + m1[node]);   // full layer-1 pre-activation input
        float a0 = 0.f, a1 = 0.f;
#pragma unroll
        for (int k = 0; k < 8; ++k) {
            float h = fmaxf(w1[k] * s + bb1[k], 0.f);
            a0 += h * w2[2 * k + 0];
            a1 += h * w2[2 * k + 1];
        }
        h2m[node] = make_float2(d * a0, d * a1);                // dis[src]*h2
        out[node] = make_float2(bb20 + d * d * a0, bb21 + d * d * a1); // bias+self
    }
}

// ---- P4: layer-2 LDS aggregation; out += dis[dst] * sum(h2m[src])
__global__ void k_layer2(const unsigned int* __restrict__ rec,
                         const unsigned int* __restrict__ bucket_base,
                         const float* __restrict__ dis,
                         const float2* __restrict__ h2m,
                         float2* __restrict__ out) {
    __shared__ float ax[NPB];
    __shared__ float ay[NPB];
    int tid = threadIdx.x, bid = blockIdx.x;
    for (int l = tid; l < NPB; l += TB) { ax[l] = 0.f; ay[l] = 0.f; }
    __syncthreads();
    unsigned int e0 = bucket_base[bid], e1 = bucket_base[bid + 1];
    for (unsigned int e = e0 + tid; e < e1; e += TB) {
        unsigned int r = rec[e];
        float2 v = h2m[r & 0x3FFFFFu];
        unsigned int dl = r >> 22;
        atomicAdd(&ax[dl], v.x);
        atomicAdd(&ay[dl], v.y);
    }
    __syncthreads();
    int node0 = bid << 10;
    int nn = min(NPB, N_NODES - node0);
    for (int l = tid; l < nn; l += TB) {
        int node = node0 + l;
        float d = dis[node];
        float2 o = out[node];
        out[node] = make_float2(o.x + d * ax[l], o.y + d * ay[l]);
    }
}

// ===========================================================================
// Fallback path (R1 kernels): global atomics — used only if ws too small.
// ===========================================================================
__global__ void k_count_deg(const int* __restrict__ dst, int E,
                            unsigned int* __restrict__ deg) {
    int i = blockIdx.x * blockDim.x + threadIdx.x;
    int stride = gridDim.x * blockDim.x;
    for (int e = i; e < E; e += stride) atomicAdd(&deg[dst[e]], 1u);
}
__global__ void k_dis_sinit(const unsigned int* __restrict__ deg,
                            const float* __restrict__ x,
                            float* __restrict__ dis, float* __restrict__ s, int N) {
    int i = blockIdx.x * blockDim.x + threadIdx.x;
    if (i < N) {
        float r = rsqrtf((float)(deg[i] + 1u));
        dis[i] = r;
        s[i] = r * r * x[i];
    }
}
__global__ void k_agg1(const int* __restrict__ src, const int* __restrict__ dst,
                       int E, const float* __restrict__ dis,
                       const float* __restrict__ x, float* __restrict__ s) {
    int i = blockIdx.x * blockDim.x + threadIdx.x;
    int stride = gridDim.x * blockDim.x;
    for (int e = i; e < E; e += stride) {
        int sj = src[e], dj = dst[e];
        atomicAdd(&s[dj], dis[sj] * dis[dj] * x[sj]);
    }
}
__global__ void k_node2(const float* __restrict__ s, const float* __restrict__ dis,
                        const float* __restrict__ W1, const float* __restrict__ b1,
                        const float* __restrict__ W2, const float* __restrict__ b2,
                        float2* __restrict__ h2, float2* __restrict__ out, int N) {
    int i = blockIdx.x * blockDim.x + threadIdx.x;
    if (i >= N) return;
    float si = s[i];
    float a0 = 0.f, a1 = 0.f;
#pragma unroll
    for (int k = 0; k < 8; ++k) {
        float hk = fmaxf(W1[k] * si + b1[k], 0.f);
        a0 += hk * W2[2 * k + 0];
        a1 += hk * W2[2 * k + 1];
    }
    h2[i] = make_float2(a0, a1);
    float r2 = dis[i] * dis[i];
    out[i] = make_float2(b2[0] + r2 * a0, b2[1] + r2 * a1);
}
__global__ void k_agg2(const int* __restrict__ src, const int* __restrict__ dst,
                       int E, const float* __restrict__ dis,
                       const float2* __restrict__ h2, float* __restrict__ out) {
    int i = blockIdx.x * blockDim.x + threadIdx.x;
    int stride = gridDim.x * blockDim.x;
    for (int e = i; e < E; e += stride) {
        int sj = src[e], dj = dst[e];
        float n = dis[sj] * dis[dj];
        float2 v = h2[sj];
        atomicAdd(&out[2 * dj + 0], n * v.x);
        atomicAdd(&out[2 * dj + 1], n * v.y);
    }
}

// ===========================================================================
extern "C" void kernel_launch(void* const* d_in, const int* in_sizes, int n_in,
                              void* d_out, int out_size, void* d_ws, size_t ws_size,
                              hipStream_t stream) {
    const float* x  = (const float*)d_in[0];
    const int*   ei = (const int*)d_in[1];   // [2, E] flat: src row, then dst row
    const float* W1 = (const float*)d_in[2];
    const float* b1 = (const float*)d_in[3];
    const float* W2 = (const float*)d_in[4];
    const float* b2 = (const float*)d_in[5];

    const int N = N_NODES;
    const int E = in_sizes[1] / 2;
    const int* src = ei;
    const int* dst = ei + E;
    float* out = (float*)d_out;

    const int nchunks = (E + CHUNK - 1) / CHUNK;

    // ---- workspace layout (fast path) ----
    char* ws = (char*)d_ws;
    size_t off_counts = 0;                                   // NBUCK u32
    size_t off_bb     = 4096;                                // NBUCK+1 u32
    size_t off_aux    = 8192;                                // nchunks*NBUCK u32
    size_t aux_bytes  = (size_t)nchunks * NBUCK * 4;
    size_t off_dis    = (off_aux + aux_bytes + 255) & ~(size_t)255;
    size_t off_m1     = off_dis + (size_t)N * 4;
    size_t off_h2m    = off_m1 + (size_t)N * 4;
    size_t off_rec    = off_h2m + (size_t)N * 8;
    size_t need       = off_rec + (size_t)E * 4;

    if (ws_size >= need) {
        unsigned int* counts = (unsigned int*)(ws + off_counts);
        unsigned int* bb     = (unsigned int*)(ws + off_bb);
        unsigned int* aux    = (unsigned int*)(ws + off_aux);
        float* dis           = (float*)(ws + off_dis);
        float* m1            = (float*)(ws + off_m1);
        float2* h2m          = (float2*)(ws + off_h2m);
        unsigned int* rec    = (unsigned int*)(ws + off_rec);

        hipMemsetAsync(counts, 0, NBUCK * sizeof(unsigned int), stream);
        k_bin_count<<<nchunks, TB, 0, stream>>>(dst, E, counts, aux);
        k_scan<<<1, 512, 0, stream>>>(counts, bb);
        k_bin_scatter<<<nchunks, TB, 0, stream>>>(src, dst, E, bb, aux, rec);
        k_deg_dis<<<NBUCK, TB, 0, stream>>>(rec, bb, x, dis, m1);
        k_layer1<<<NBUCK, TB, 0, stream>>>(rec, bb, dis, m1, W1, b1, W2, b2,
                                           h2m, (float2*)out);
        k_layer2<<<NBUCK, TB, 0, stream>>>(rec, bb, dis, h2m, (float2*)out);
    } else {
        // fallback: R1 global-atomic path (needs 10 MB ws)
        unsigned int* deg = (unsigned int*)(ws);
        float* dis        = (float*)(ws + (size_t)N * 4);
        float* s          = (float*)(ws + (size_t)N * 8);
        float2* h2        = (float2*)(ws + (size_t)N * 12);
        hipMemsetAsync(deg, 0, (size_t)N * sizeof(unsigned int), stream);
        int nodeBlocks = (N + TB - 1) / TB;
        int edgeBlocks = (E + TB - 1) / TB;
        k_count_deg<<<edgeBlocks, TB, 0, stream>>>(dst, E, deg);
        k_dis_sinit<<<nodeBlocks, TB, 0, stream>>>(deg, x, dis, s, N);
        k_agg1<<<edgeBlocks, TB, 0, stream>>>(src, dst, E, dis, x, s);
        k_node2<<<nodeBlocks, TB, 0, stream>>>(s, dis, W1, b1, W2, b2, h2,
                                               (float2*)out, N);
        k_agg2<<<edgeBlocks, TB, 0, stream>>>(src, dst, E, dis, h2, out);
    }
}

// Round 3
// 629.842 us; speedup vs baseline: 4.9174x; 1.2612x over previous
//
#include <hip/hip_runtime.h>

#define N_NODES 500000
#define NPB 1024                            // nodes per bucket (dst >> 10)
#define NBUCK ((N_NODES + NPB - 1) / NPB)   // 489
#define BIN_CHUNK 32768                     // edges per binning workgroup
#define BTB 1024                            // threads per binning/record WG

// ===========================================================================
// Fast path: bin edges by dst bucket (exact two-phase), LDS-accumulate.
// All heavy kernels use 1024-thread WGs (16 waves) for ~full occupancy.
// ===========================================================================

// ---- P1a: per-chunk bucket histogram; reserve via 1 atomic/(wg,bucket)
__global__ __launch_bounds__(BTB) void k_bin_count(
        const int* __restrict__ dst, int E,
        unsigned int* __restrict__ counts, unsigned int* __restrict__ aux) {
    __shared__ unsigned int hist[NBUCK];
    int tid = threadIdx.x, bid = blockIdx.x;
    for (int b = tid; b < NBUCK; b += BTB) hist[b] = 0;
    __syncthreads();
    int e0 = bid * BIN_CHUNK;
    int e1 = min(E, e0 + BIN_CHUNK);
    int nv = (e1 - e0) >> 2;                       // chunk lengths are %4
    const int4* d4 = (const int4*)(dst + e0);
    for (int i = tid; i < nv; i += BTB) {
        int4 d = d4[i];
        atomicAdd(&hist[(unsigned)d.x >> 10], 1u);
        atomicAdd(&hist[(unsigned)d.y >> 10], 1u);
        atomicAdd(&hist[(unsigned)d.z >> 10], 1u);
        atomicAdd(&hist[(unsigned)d.w >> 10], 1u);
    }
    for (int e = e0 + (nv << 2) + tid; e < e1; e += BTB)   // safety tail
        atomicAdd(&hist[(unsigned)dst[e] >> 10], 1u);
    __syncthreads();
    unsigned int* row = aux + (size_t)bid * NBUCK;
    for (int b = tid; b < NBUCK; b += BTB)
        row[b] = atomicAdd(&counts[b], hist[b]);   // old value = my base
}

// ---- exclusive prefix over bucket counts (single WG)
__global__ void k_scan(const unsigned int* __restrict__ counts,
                       unsigned int* __restrict__ bucket_base) {
    __shared__ unsigned int sc[512];
    int tid = threadIdx.x;
    unsigned int v = (tid < NBUCK) ? counts[tid] : 0u;
    sc[tid] = v;
    __syncthreads();
    for (int off = 1; off < 512; off <<= 1) {
        unsigned int t = (tid >= off) ? sc[tid - off] : 0u;
        __syncthreads();
        sc[tid] += t;
        __syncthreads();
    }
    if (tid <= NBUCK) bucket_base[tid] = sc[tid] - v;  // exclusive; [NBUCK]=E
}

// ---- P1b: scatter packed records (dstlocal<<22 | src) into bucket regions
__global__ __launch_bounds__(BTB) void k_bin_scatter(
        const int* __restrict__ src, const int* __restrict__ dst, int E,
        const unsigned int* __restrict__ bucket_base,
        const unsigned int* __restrict__ aux, unsigned int* __restrict__ rec) {
    __shared__ unsigned int cur[NBUCK];
    int tid = threadIdx.x, bid = blockIdx.x;
    const unsigned int* row = aux + (size_t)bid * NBUCK;
    for (int b = tid; b < NBUCK; b += BTB) cur[b] = bucket_base[b] + row[b];
    __syncthreads();
    int e0 = bid * BIN_CHUNK;
    int e1 = min(E, e0 + BIN_CHUNK);
    int nv = (e1 - e0) >> 2;
    const int4* d4 = (const int4*)(dst + e0);
    const int4* s4 = (const int4*)(src + e0);
    for (int i = tid; i < nv; i += BTB) {
        int4 d = d4[i];
        int4 s = s4[i];
        {
            unsigned b = (unsigned)d.x >> 10;
            unsigned p = atomicAdd(&cur[b], 1u);
            rec[p] = (((unsigned)d.x & (NPB - 1u)) << 22) | (unsigned)s.x;
        }
        {
            unsigned b = (unsigned)d.y >> 10;
            unsigned p = atomicAdd(&cur[b], 1u);
            rec[p] = (((unsigned)d.y & (NPB - 1u)) << 22) | (unsigned)s.y;
        }
        {
            unsigned b = (unsigned)d.z >> 10;
            unsigned p = atomicAdd(&cur[b], 1u);
            rec[p] = (((unsigned)d.z & (NPB - 1u)) << 22) | (unsigned)s.z;
        }
        {
            unsigned b = (unsigned)d.w >> 10;
            unsigned p = atomicAdd(&cur[b], 1u);
            rec[p] = (((unsigned)d.w & (NPB - 1u)) << 22) | (unsigned)s.w;
        }
    }
    for (int e = e0 + (nv << 2) + tid; e < e1; e += BTB) {  // safety tail
        unsigned d = (unsigned)dst[e];
        unsigned b = d >> 10;
        unsigned p = atomicAdd(&cur[b], 1u);
        rec[p] = ((d & (NPB - 1u)) << 22) | (unsigned)src[e];
    }
}

// ---- P2: per-bucket degree -> dis = rsqrt(deg+1), m1 = dis*x
__global__ __launch_bounds__(BTB) void k_deg_dis(
        const unsigned int* __restrict__ rec,
        const unsigned int* __restrict__ bucket_base,
        const float* __restrict__ x,
        float* __restrict__ dis, float* __restrict__ m1) {
    __shared__ unsigned int cnt[NPB];
    int tid = threadIdx.x, bid = blockIdx.x;
    for (int l = tid; l < NPB; l += BTB) cnt[l] = 0;
    __syncthreads();
    unsigned int e0 = bucket_base[bid], e1 = bucket_base[bid + 1];
    for (unsigned int e = e0 + tid; e < e1; e += BTB)
        atomicAdd(&cnt[rec[e] >> 22], 1u);
    __syncthreads();
    int node0 = bid << 10;
    int nn = min(NPB, N_NODES - node0);
    for (int l = tid; l < nn; l += BTB) {
        int node = node0 + l;
        float r = rsqrtf((float)(cnt[l] + 1u));    // +1 self-loop; always > 0
        dis[node] = r;
        m1[node] = r * x[node];
    }
}

// ---- P3: layer-1 LDS aggregation + node MLP; writes h2m and out(self+bias)
__global__ __launch_bounds__(BTB) void k_layer1(
        const unsigned int* __restrict__ rec,
        const unsigned int* __restrict__ bucket_base,
        const float* __restrict__ dis, const float* __restrict__ m1,
        const float* __restrict__ W1, const float* __restrict__ b1,
        const float* __restrict__ W2, const float* __restrict__ b2,
        float2* __restrict__ h2m, float2* __restrict__ out) {
    __shared__ float acc[NPB];
    int tid = threadIdx.x, bid = blockIdx.x;
    for (int l = tid; l < NPB; l += BTB) acc[l] = 0.f;
    __syncthreads();
    unsigned int e0 = bucket_base[bid], e1 = bucket_base[bid + 1];
    for (unsigned int e = e0 + tid; e < e1; e += BTB) {
        unsigned int r = rec[e];
        atomicAdd(&acc[r >> 22], m1[r & 0x3FFFFFu]);
    }
    __syncthreads();
    int node0 = bid << 10;
    int nn = min(NPB, N_NODES - node0);
    float w1[8], bb1[8], w2[16];
    float bb20 = b2[0], bb21 = b2[1];
#pragma unroll
    for (int k = 0; k < 8; ++k) { w1[k] = W1[k]; bb1[k] = b1[k]; }
#pragma unroll
    for (int k = 0; k < 16; ++k) w2[k] = W2[k];
    for (int l = tid; l < nn; l += BTB) {
        int node = node0 + l;
        float d = dis[node];
        float s = d * (acc[l] + m1[node]);
        float a0 = 0.f, a1 = 0.f;
#pragma unroll
        for (int k = 0; k < 8; ++k) {
            float h = fmaxf(w1[k] * s + bb1[k], 0.f);
            a0 += h * w2[2 * k + 0];
            a1 += h * w2[2 * k + 1];
        }
        h2m[node] = make_float2(d * a0, d * a1);                    // dis[src]*h2
        out[node] = make_float2(bb20 + d * d * a0, bb21 + d * d * a1);
    }
}

// ---- P4: layer-2 LDS aggregation; out += dis[dst] * sum(h2m[src])
__global__ __launch_bounds__(BTB) void k_layer2(
        const unsigned int* __restrict__ rec,
        const unsigned int* __restrict__ bucket_base,
        const float* __restrict__ dis, const float2* __restrict__ h2m,
        float2* __restrict__ out) {
    __shared__ float ax[NPB];
    __shared__ float ay[NPB];
    int tid = threadIdx.x, bid = blockIdx.x;
    for (int l = tid; l < NPB; l += BTB) { ax[l] = 0.f; ay[l] = 0.f; }
    __syncthreads();
    unsigned int e0 = bucket_base[bid], e1 = bucket_base[bid + 1];
    for (unsigned int e = e0 + tid; e < e1; e += BTB) {
        unsigned int r = rec[e];
        float2 v = h2m[r & 0x3FFFFFu];
        unsigned int dl = r >> 22;
        atomicAdd(&ax[dl], v.x);
        atomicAdd(&ay[dl], v.y);
    }
    __syncthreads();
    int node0 = bid << 10;
    int nn = min(NPB, N_NODES - node0);
    for (int l = tid; l < nn; l += BTB) {
        int node = node0 + l;
        float d = dis[node];
        float2 o = out[node];
        out[node] = make_float2(o.x + d * ax[l], o.y + d * ay[l]);
    }
}

// ===========================================================================
// Fallback path (R1 kernels): global atomics — used only if ws too small.
// ===========================================================================
__global__ void k_count_deg(const int* __restrict__ dst, int E,
                            unsigned int* __restrict__ deg) {
    int i = blockIdx.x * blockDim.x + threadIdx.x;
    int stride = gridDim.x * blockDim.x;
    for (int e = i; e < E; e += stride) atomicAdd(&deg[dst[e]], 1u);
}
__global__ void k_dis_sinit(const unsigned int* __restrict__ deg,
                            const float* __restrict__ x,
                            float* __restrict__ dis, float* __restrict__ s, int N) {
    int i = blockIdx.x * blockDim.x + threadIdx.x;
    if (i < N) {
        float r = rsqrtf((float)(deg[i] + 1u));
        dis[i] = r;
        s[i] = r * r * x[i];
    }
}
__global__ void k_agg1(const int* __restrict__ src, const int* __restrict__ dst,
                       int E, const float* __restrict__ dis,
                       const float* __restrict__ x, float* __restrict__ s) {
    int i = blockIdx.x * blockDim.x + threadIdx.x;
    int stride = gridDim.x * blockDim.x;
    for (int e = i; e < E; e += stride) {
        int sj = src[e], dj = dst[e];
        atomicAdd(&s[dj], dis[sj] * dis[dj] * x[sj]);
    }
}
__global__ void k_node2(const float* __restrict__ s, const float* __restrict__ dis,
                        const float* __restrict__ W1, const float* __restrict__ b1,
                        const float* __restrict__ W2, const float* __restrict__ b2,
                        float2* __restrict__ h2, float2* __restrict__ out, int N) {
    int i = blockIdx.x * blockDim.x + threadIdx.x;
    if (i >= N) return;
    float si = s[i];
    float a0 = 0.f, a1 = 0.f;
#pragma unroll
    for (int k = 0; k < 8; ++k) {
        float hk = fmaxf(W1[k] * si + b1[k], 0.f);
        a0 += hk * W2[2 * k + 0];
        a1 += hk * W2[2 * k + 1];
    }
    h2[i] = make_float2(a0, a1);
    float r2 = dis[i] * dis[i];
    out[i] = make_float2(b2[0] + r2 * a0, b2[1] + r2 * a1);
}
__global__ void k_agg2(const int* __restrict__ src, const int* __restrict__ dst,
                       int E, const float* __restrict__ dis,
                       const float2* __restrict__ h2, float* __restrict__ out) {
    int i = blockIdx.x * blockDim.x + threadIdx.x;
    int stride = gridDim.x * blockDim.x;
    for (int e = i; e < E; e += stride) {
        int sj = src[e], dj = dst[e];
        float n = dis[sj] * dis[dj];
        float2 v = h2[sj];
        atomicAdd(&out[2 * dj + 0], n * v.x);
        atomicAdd(&out[2 * dj + 1], n * v.y);
    }
}

// ===========================================================================
extern "C" void kernel_launch(void* const* d_in, const int* in_sizes, int n_in,
                              void* d_out, int out_size, void* d_ws, size_t ws_size,
                              hipStream_t stream) {
    const float* x  = (const float*)d_in[0];
    const int*   ei = (const int*)d_in[1];   // [2, E] flat: src row, then dst row
    const float* W1 = (const float*)d_in[2];
    const float* b1 = (const float*)d_in[3];
    const float* W2 = (const float*)d_in[4];
    const float* b2 = (const float*)d_in[5];

    const int N = N_NODES;
    const int E = in_sizes[1] / 2;
    const int* src = ei;
    const int* dst = ei + E;
    float* out = (float*)d_out;

    const int nchunks = (E + BIN_CHUNK - 1) / BIN_CHUNK;

    // ---- workspace layout (fast path) ----
    char* ws = (char*)d_ws;
    size_t off_counts = 0;                                   // NBUCK u32
    size_t off_bb     = 4096;                                // NBUCK+1 u32
    size_t off_aux    = 8192;                                // nchunks*NBUCK u32
    size_t aux_bytes  = (size_t)nchunks * NBUCK * 4;
    size_t off_dis    = (off_aux + aux_bytes + 255) & ~(size_t)255;
    size_t off_m1     = off_dis + (size_t)N * 4;
    size_t off_h2m    = off_m1 + (size_t)N * 4;
    size_t off_rec    = off_h2m + (size_t)N * 8;
    size_t need       = off_rec + (size_t)E * 4;

    if (ws_size >= need) {
        unsigned int* counts = (unsigned int*)(ws + off_counts);
        unsigned int* bb     = (unsigned int*)(ws + off_bb);
        unsigned int* aux    = (unsigned int*)(ws + off_aux);
        float* dis           = (float*)(ws + off_dis);
        float* m1            = (float*)(ws + off_m1);
        float2* h2m          = (float2*)(ws + off_h2m);
        unsigned int* rec    = (unsigned int*)(ws + off_rec);

        hipMemsetAsync(counts, 0, NBUCK * sizeof(unsigned int), stream);
        k_bin_count<<<nchunks, BTB, 0, stream>>>(dst, E, counts, aux);
        k_scan<<<1, 512, 0, stream>>>(counts, bb);
        k_bin_scatter<<<nchunks, BTB, 0, stream>>>(src, dst, E, bb, aux, rec);
        k_deg_dis<<<NBUCK, BTB, 0, stream>>>(rec, bb, x, dis, m1);
        k_layer1<<<NBUCK, BTB, 0, stream>>>(rec, bb, dis, m1, W1, b1, W2, b2,
                                            h2m, (float2*)out);
        k_layer2<<<NBUCK, BTB, 0, stream>>>(rec, bb, dis, h2m, (float2*)out);
    } else {
        // fallback: R1 global-atomic path (needs 10 MB ws)
        unsigned int* deg = (unsigned int*)(ws);
        float* dis        = (float*)(ws + (size_t)N * 4);
        float* s          = (float*)(ws + (size_t)N * 8);
        float2* h2        = (float2*)(ws + (size_t)N * 12);
        hipMemsetAsync(deg, 0, (size_t)N * sizeof(unsigned int), stream);
        const int TB = 256;
        int nodeBlocks = (N + TB - 1) / TB;
        int edgeBlocks = (E + TB - 1) / TB;
        k_count_deg<<<edgeBlocks, TB, 0, stream>>>(dst, E, deg);
        k_dis_sinit<<<nodeBlocks, TB, 0, stream>>>(deg, x, dis, s, N);
        k_agg1<<<edgeBlocks, TB, 0, stream>>>(src, dst, E, dis, x, s);
        k_node2<<<nodeBlocks, TB, 0, stream>>>(s, dis, W1, b1, W2, b2, h2,
                                               (float2*)out, N);
        k_agg2<<<edgeBlocks, TB, 0, stream>>>(src, dst, E, dis, h2, out);
    }
}

// Round 4
// 618.164 us; speedup vs baseline: 5.0103x; 1.0189x over previous
//
#include <hip/hip_runtime.h>

#define N_NODES 500000
#define NPB 1024                            // nodes per bucket (dst >> 10)
#define NBUCK ((N_NODES + NPB - 1) / NPB)   // 489
#define BIN_CHUNK 32768                     // edges per binning workgroup
#define BTB 1024                            // threads per binning/record WG
#define SRCMASK 0x3FFFFFu

// ===========================================================================
// Fast path: bin edges by dst bucket (exact two-phase), LDS-accumulate.
// Record passes batch 4 records/thread (int4) for 4x memory-level parallelism.
// ===========================================================================

// ---- P1a: per-chunk bucket histogram; reserve via 1 atomic/(wg,bucket)
__global__ __launch_bounds__(BTB) void k_bin_count(
        const int* __restrict__ dst, int E,
        unsigned int* __restrict__ counts, unsigned int* __restrict__ aux) {
    __shared__ unsigned int hist[NBUCK];
    int tid = threadIdx.x, bid = blockIdx.x;
    for (int b = tid; b < NBUCK; b += BTB) hist[b] = 0;
    __syncthreads();
    int e0 = bid * BIN_CHUNK;
    int e1 = min(E, e0 + BIN_CHUNK);
    int nv = (e1 - e0) >> 2;
    const int4* d4 = (const int4*)(dst + e0);
    for (int i = tid; i < nv; i += BTB) {
        int4 d = d4[i];
        atomicAdd(&hist[(unsigned)d.x >> 10], 1u);
        atomicAdd(&hist[(unsigned)d.y >> 10], 1u);
        atomicAdd(&hist[(unsigned)d.z >> 10], 1u);
        atomicAdd(&hist[(unsigned)d.w >> 10], 1u);
    }
    for (int e = e0 + (nv << 2) + tid; e < e1; e += BTB)
        atomicAdd(&hist[(unsigned)dst[e] >> 10], 1u);
    __syncthreads();
    unsigned int* row = aux + (size_t)bid * NBUCK;
    for (int b = tid; b < NBUCK; b += BTB)
        row[b] = atomicAdd(&counts[b], hist[b]);   // old value = my base
}

// ---- exclusive prefix over bucket counts (single WG)
__global__ void k_scan(const unsigned int* __restrict__ counts,
                       unsigned int* __restrict__ bucket_base) {
    __shared__ unsigned int sc[512];
    int tid = threadIdx.x;
    unsigned int v = (tid < NBUCK) ? counts[tid] : 0u;
    sc[tid] = v;
    __syncthreads();
    for (int off = 1; off < 512; off <<= 1) {
        unsigned int t = (tid >= off) ? sc[tid - off] : 0u;
        __syncthreads();
        sc[tid] += t;
        __syncthreads();
    }
    if (tid <= NBUCK) bucket_base[tid] = sc[tid] - v;  // exclusive; [NBUCK]=E
}

// ---- P1b: scatter packed records (dstlocal<<22 | src) into bucket regions
__global__ __launch_bounds__(BTB) void k_bin_scatter(
        const int* __restrict__ src, const int* __restrict__ dst, int E,
        const unsigned int* __restrict__ bucket_base,
        const unsigned int* __restrict__ aux, unsigned int* __restrict__ rec) {
    __shared__ unsigned int cur[NBUCK];
    int tid = threadIdx.x, bid = blockIdx.x;
    const unsigned int* row = aux + (size_t)bid * NBUCK;
    for (int b = tid; b < NBUCK; b += BTB) cur[b] = bucket_base[b] + row[b];
    __syncthreads();
    int e0 = bid * BIN_CHUNK;
    int e1 = min(E, e0 + BIN_CHUNK);
    int nv = (e1 - e0) >> 2;
    const int4* d4 = (const int4*)(dst + e0);
    const int4* s4 = (const int4*)(src + e0);
    for (int i = tid; i < nv; i += BTB) {
        int4 d = d4[i];
        int4 s = s4[i];
        unsigned p0 = atomicAdd(&cur[(unsigned)d.x >> 10], 1u);
        unsigned p1 = atomicAdd(&cur[(unsigned)d.y >> 10], 1u);
        unsigned p2 = atomicAdd(&cur[(unsigned)d.z >> 10], 1u);
        unsigned p3 = atomicAdd(&cur[(unsigned)d.w >> 10], 1u);
        rec[p0] = (((unsigned)d.x & (NPB - 1u)) << 22) | (unsigned)s.x;
        rec[p1] = (((unsigned)d.y & (NPB - 1u)) << 22) | (unsigned)s.y;
        rec[p2] = (((unsigned)d.z & (NPB - 1u)) << 22) | (unsigned)s.z;
        rec[p3] = (((unsigned)d.w & (NPB - 1u)) << 22) | (unsigned)s.w;
    }
    for (int e = e0 + (nv << 2) + tid; e < e1; e += BTB) {
        unsigned d = (unsigned)dst[e];
        unsigned p = atomicAdd(&cur[d >> 10], 1u);
        rec[p] = ((d & (NPB - 1u)) << 22) | (unsigned)src[e];
    }
}

// ---- P2: per-bucket degree -> dis = rsqrt(deg+1), m1 = dis*x
__global__ __launch_bounds__(BTB) void k_deg_dis(
        const unsigned int* __restrict__ rec,
        const unsigned int* __restrict__ bucket_base,
        const float* __restrict__ x,
        float* __restrict__ dis, float* __restrict__ m1) {
    __shared__ unsigned int cnt[NPB];
    int tid = threadIdx.x, bid = blockIdx.x;
    for (int l = tid; l < NPB; l += BTB) cnt[l] = 0;
    __syncthreads();
    unsigned e0 = bucket_base[bid], e1 = bucket_base[bid + 1];
    unsigned ha = min((e0 + 3u) & ~3u, e1);        // head end (aligned)
    unsigned ta = (e1 & ~3u) > ha ? (e1 & ~3u) : ha; // aligned tail start
    if (e0 + tid < ha) atomicAdd(&cnt[rec[e0 + tid] >> 22], 1u);
    const uint4* r4 = (const uint4*)rec;
    for (unsigned i = (ha >> 2) + tid; i < (ta >> 2); i += BTB) {
        uint4 r = r4[i];
        atomicAdd(&cnt[r.x >> 22], 1u);
        atomicAdd(&cnt[r.y >> 22], 1u);
        atomicAdd(&cnt[r.z >> 22], 1u);
        atomicAdd(&cnt[r.w >> 22], 1u);
    }
    if (ta + tid < e1) atomicAdd(&cnt[rec[ta + tid] >> 22], 1u);
    __syncthreads();
    int node0 = bid << 10;
    int nn = min(NPB, N_NODES - node0);
    for (int l = tid; l < nn; l += BTB) {
        int node = node0 + l;
        float r = rsqrtf((float)(cnt[l] + 1u));    // +1 self-loop; always > 0
        dis[node] = r;
        m1[node] = r * x[node];
    }
}

// ---- P3: layer-1 LDS aggregation + node MLP; writes h2m and out(self+bias)
__global__ __launch_bounds__(BTB) void k_layer1(
        const unsigned int* __restrict__ rec,
        const unsigned int* __restrict__ bucket_base,
        const float* __restrict__ dis, const float* __restrict__ m1,
        const float* __restrict__ W1, const float* __restrict__ b1,
        const float* __restrict__ W2, const float* __restrict__ b2,
        float2* __restrict__ h2m, float2* __restrict__ out) {
    __shared__ float acc[NPB];
    int tid = threadIdx.x, bid = blockIdx.x;
    for (int l = tid; l < NPB; l += BTB) acc[l] = 0.f;
    __syncthreads();
    unsigned e0 = bucket_base[bid], e1 = bucket_base[bid + 1];
    unsigned ha = min((e0 + 3u) & ~3u, e1);
    unsigned ta = (e1 & ~3u) > ha ? (e1 & ~3u) : ha;
    if (e0 + tid < ha) {
        unsigned r = rec[e0 + tid];
        atomicAdd(&acc[r >> 22], m1[r & SRCMASK]);
    }
    const uint4* r4 = (const uint4*)rec;
    for (unsigned i = (ha >> 2) + tid; i < (ta >> 2); i += BTB) {
        uint4 r = r4[i];
        float v0 = m1[r.x & SRCMASK];   // 4 independent gathers in flight
        float v1 = m1[r.y & SRCMASK];
        float v2 = m1[r.z & SRCMASK];
        float v3 = m1[r.w & SRCMASK];
        atomicAdd(&acc[r.x >> 22], v0);
        atomicAdd(&acc[r.y >> 22], v1);
        atomicAdd(&acc[r.z >> 22], v2);
        atomicAdd(&acc[r.w >> 22], v3);
    }
    if (ta + tid < e1) {
        unsigned r = rec[ta + tid];
        atomicAdd(&acc[r >> 22], m1[r & SRCMASK]);
    }
    __syncthreads();
    int node0 = bid << 10;
    int nn = min(NPB, N_NODES - node0);
    float w1[8], bb1[8], w2[16];
    float bb20 = b2[0], bb21 = b2[1];
#pragma unroll
    for (int k = 0; k < 8; ++k) { w1[k] = W1[k]; bb1[k] = b1[k]; }
#pragma unroll
    for (int k = 0; k < 16; ++k) w2[k] = W2[k];
    for (int l = tid; l < nn; l += BTB) {
        int node = node0 + l;
        float d = dis[node];
        float s = d * (acc[l] + m1[node]);
        float a0 = 0.f, a1 = 0.f;
#pragma unroll
        for (int k = 0; k < 8; ++k) {
            float h = fmaxf(w1[k] * s + bb1[k], 0.f);
            a0 += h * w2[2 * k + 0];
            a1 += h * w2[2 * k + 1];
        }
        h2m[node] = make_float2(d * a0, d * a1);                    // dis[src]*h2
        out[node] = make_float2(bb20 + d * d * a0, bb21 + d * d * a1);
    }
}

// ---- P4: layer-2 LDS aggregation; out += dis[dst] * sum(h2m[src])
__global__ __launch_bounds__(BTB) void k_layer2(
        const unsigned int* __restrict__ rec,
        const unsigned int* __restrict__ bucket_base,
        const float* __restrict__ dis, const float2* __restrict__ h2m,
        float2* __restrict__ out) {
    __shared__ float ax[NPB];
    __shared__ float ay[NPB];
    int tid = threadIdx.x, bid = blockIdx.x;
    for (int l = tid; l < NPB; l += BTB) { ax[l] = 0.f; ay[l] = 0.f; }
    __syncthreads();
    unsigned e0 = bucket_base[bid], e1 = bucket_base[bid + 1];
    unsigned ha = min((e0 + 3u) & ~3u, e1);
    unsigned ta = (e1 & ~3u) > ha ? (e1 & ~3u) : ha;
    if (e0 + tid < ha) {
        unsigned r = rec[e0 + tid];
        float2 v = h2m[r & SRCMASK];
        atomicAdd(&ax[r >> 22], v.x);
        atomicAdd(&ay[r >> 22], v.y);
    }
    const uint4* r4 = (const uint4*)rec;
    for (unsigned i = (ha >> 2) + tid; i < (ta >> 2); i += BTB) {
        uint4 r = r4[i];
        float2 v0 = h2m[r.x & SRCMASK];   // 4 independent 8B gathers
        float2 v1 = h2m[r.y & SRCMASK];
        float2 v2 = h2m[r.z & SRCMASK];
        float2 v3 = h2m[r.w & SRCMASK];
        atomicAdd(&ax[r.x >> 22], v0.x);
        atomicAdd(&ay[r.x >> 22], v0.y);
        atomicAdd(&ax[r.y >> 22], v1.x);
        atomicAdd(&ay[r.y >> 22], v1.y);
        atomicAdd(&ax[r.z >> 22], v2.x);
        atomicAdd(&ay[r.z >> 22], v2.y);
        atomicAdd(&ax[r.w >> 22], v3.x);
        atomicAdd(&ay[r.w >> 22], v3.y);
    }
    if (ta + tid < e1) {
        unsigned r = rec[ta + tid];
        float2 v = h2m[r & SRCMASK];
        atomicAdd(&ax[r >> 22], v.x);
        atomicAdd(&ay[r >> 22], v.y);
    }
    __syncthreads();
    int node0 = bid << 10;
    int nn = min(NPB, N_NODES - node0);
    for (int l = tid; l < nn; l += BTB) {
        int node = node0 + l;
        float d = dis[node];
        float2 o = out[node];
        out[node] = make_float2(o.x + d * ax[l], o.y + d * ay[l]);
    }
}

// ===========================================================================
// Fallback path (R1 kernels): global atomics — used only if ws too small.
// ===========================================================================
__global__ void k_count_deg(const int* __restrict__ dst, int E,
                            unsigned int* __restrict__ deg) {
    int i = blockIdx.x * blockDim.x + threadIdx.x;
    int stride = gridDim.x * blockDim.x;
    for (int e = i; e < E; e += stride) atomicAdd(&deg[dst[e]], 1u);
}
__global__ void k_dis_sinit(const unsigned int* __restrict__ deg,
                            const float* __restrict__ x,
                            float* __restrict__ dis, float* __restrict__ s, int N) {
    int i = blockIdx.x * blockDim.x + threadIdx.x;
    if (i < N) {
        float r = rsqrtf((float)(deg[i] + 1u));
        dis[i] = r;
        s[i] = r * r * x[i];
    }
}
__global__ void k_agg1(const int* __restrict__ src, const int* __restrict__ dst,
                       int E, const float* __restrict__ dis,
                       const float* __restrict__ x, float* __restrict__ s) {
    int i = blockIdx.x * blockDim.x + threadIdx.x;
    int stride = gridDim.x * blockDim.x;
    for (int e = i; e < E; e += stride) {
        int sj = src[e], dj = dst[e];
        atomicAdd(&s[dj], dis[sj] * dis[dj] * x[sj]);
    }
}
__global__ void k_node2(const float* __restrict__ s, const float* __restrict__ dis,
                        const float* __restrict__ W1, const float* __restrict__ b1,
                        const float* __restrict__ W2, const float* __restrict__ b2,
                        float2* __restrict__ h2, float2* __restrict__ out, int N) {
    int i = blockIdx.x * blockDim.x + threadIdx.x;
    if (i >= N) return;
    float si = s[i];
    float a0 = 0.f, a1 = 0.f;
#pragma unroll
    for (int k = 0; k < 8; ++k) {
        float hk = fmaxf(W1[k] * si + b1[k], 0.f);
        a0 += hk * W2[2 * k + 0];
        a1 += hk * W2[2 * k + 1];
    }
    h2[i] = make_float2(a0, a1);
    float r2 = dis[i] * dis[i];
    out[i] = make_float2(b2[0] + r2 * a0, b2[1] + r2 * a1);
}
__global__ void k_agg2(const int* __restrict__ src, const int* __restrict__ dst,
                       int E, const float* __restrict__ dis,
                       const float2* __restrict__ h2, float* __restrict__ out) {
    int i = blockIdx.x * blockDim.x + threadIdx.x;
    int stride = gridDim.x * blockDim.x;
    for (int e = i; e < E; e += stride) {
        int sj = src[e], dj = dst[e];
        float n = dis[sj] * dis[dj];
        float2 v = h2[sj];
        atomicAdd(&out[2 * dj + 0], n * v.x);
        atomicAdd(&out[2 * dj + 1], n * v.y);
    }
}

// ===========================================================================
extern "C" void kernel_launch(void* const* d_in, const int* in_sizes, int n_in,
                              void* d_out, int out_size, void* d_ws, size_t ws_size,
                              hipStream_t stream) {
    const float* x  = (const float*)d_in[0];
    const int*   ei = (const int*)d_in[1];   // [2, E] flat: src row, then dst row
    const float* W1 = (const float*)d_in[2];
    const float* b1 = (const float*)d_in[3];
    const float* W2 = (const float*)d_in[4];
    const float* b2 = (const float*)d_in[5];

    const int N = N_NODES;
    const int E = in_sizes[1] / 2;
    const int* src = ei;
    const int* dst = ei + E;
    float* out = (float*)d_out;

    const int nchunks = (E + BIN_CHUNK - 1) / BIN_CHUNK;

    // ---- workspace layout (fast path) ----
    char* ws = (char*)d_ws;
    size_t off_counts = 0;                                   // NBUCK u32
    size_t off_bb     = 4096;                                // NBUCK+1 u32
    size_t off_aux    = 8192;                                // nchunks*NBUCK u32
    size_t aux_bytes  = (size_t)nchunks * NBUCK * 4;
    size_t off_dis    = (off_aux + aux_bytes + 255) & ~(size_t)255;
    size_t off_m1     = off_dis + (size_t)N * 4;
    size_t off_h2m    = off_m1 + (size_t)N * 4;
    size_t off_rec    = off_h2m + (size_t)N * 8;
    size_t need       = off_rec + (size_t)E * 4 + 16;

    if (ws_size >= need) {
        unsigned int* counts = (unsigned int*)(ws + off_counts);
        unsigned int* bb     = (unsigned int*)(ws + off_bb);
        unsigned int* aux    = (unsigned int*)(ws + off_aux);
        float* dis           = (float*)(ws + off_dis);
        float* m1            = (float*)(ws + off_m1);
        float2* h2m          = (float2*)(ws + off_h2m);
        unsigned int* rec    = (unsigned int*)(ws + off_rec);

        hipMemsetAsync(counts, 0, NBUCK * sizeof(unsigned int), stream);
        k_bin_count<<<nchunks, BTB, 0, stream>>>(dst, E, counts, aux);
        k_scan<<<1, 512, 0, stream>>>(counts, bb);
        k_bin_scatter<<<nchunks, BTB, 0, stream>>>(src, dst, E, bb, aux, rec);
        k_deg_dis<<<NBUCK, BTB, 0, stream>>>(rec, bb, x, dis, m1);
        k_layer1<<<NBUCK, BTB, 0, stream>>>(rec, bb, dis, m1, W1, b1, W2, b2,
                                            h2m, (float2*)out);
        k_layer2<<<NBUCK, BTB, 0, stream>>>(rec, bb, dis, h2m, (float2*)out);
    } else {
        // fallback: R1 global-atomic path (needs 10 MB ws)
        unsigned int* deg = (unsigned int*)(ws);
        float* dis        = (float*)(ws + (size_t)N * 4);
        float* s          = (float*)(ws + (size_t)N * 8);
        float2* h2        = (float2*)(ws + (size_t)N * 12);
        hipMemsetAsync(deg, 0, (size_t)N * sizeof(unsigned int), stream);
        const int TB = 256;
        int nodeBlocks = (N + TB - 1) / TB;
        int edgeBlocks = (E + TB - 1) / TB;
        k_count_deg<<<edgeBlocks, TB, 0, stream>>>(dst, E, deg);
        k_dis_sinit<<<nodeBlocks, TB, 0, stream>>>(deg, x, dis, s, N);
        k_agg1<<<edgeBlocks, TB, 0, stream>>>(src, dst, E, dis, x, s);
        k_node2<<<nodeBlocks, TB, 0, stream>>>(s, dis, W1, b1, W2, b2, h2,
                                               (float2*)out, N);
        k_agg2<<<edgeBlocks, TB, 0, stream>>>(src, dst, E, dis, h2, out);
    }
}

// Round 5
// 611.441 us; speedup vs baseline: 5.0654x; 1.0110x over previous
//
#include <hip/hip_runtime.h>

#define N_NODES 500000
#define NPB 1024                            // nodes per bucket (dst >> 10)
#define NBUCK ((N_NODES + NPB - 1) / NPB)   // 489
#define BIN_CHUNK 32768                     // edges per binning workgroup
#define BTB 1024                            // threads per binning/record WG
#define SRCMASK 0x3FFFFFu

typedef int  v4i __attribute__((ext_vector_type(4)));
typedef unsigned int v4u __attribute__((ext_vector_type(4)));

// Non-temporal (evict-first) loads: keep streaming data from thrashing L2 so
// the gather tables (m1: 2MB, h2m: 4MB) stay L2-resident per XCD.
__device__ inline v4i nt_load4i(const int* p) {
    return __builtin_nontemporal_load((const v4i*)p);
}
__device__ inline v4u nt_load4u(const unsigned int* p) {
    return __builtin_nontemporal_load((const v4u*)p);
}
__device__ inline int nt_load1i(const int* p) {
    return __builtin_nontemporal_load(p);
}
__device__ inline unsigned int nt_load1u(const unsigned int* p) {
    return __builtin_nontemporal_load(p);
}

// ===========================================================================
// Fast path: bin edges by dst bucket (exact two-phase), LDS-accumulate.
// ===========================================================================

// ---- P1a: per-chunk bucket histogram; reserve via 1 atomic/(wg,bucket)
__global__ __launch_bounds__(BTB) void k_bin_count(
        const int* __restrict__ dst, int E,
        unsigned int* __restrict__ counts, unsigned int* __restrict__ aux) {
    __shared__ unsigned int hist[NBUCK];
    int tid = threadIdx.x, bid = blockIdx.x;
    for (int b = tid; b < NBUCK; b += BTB) hist[b] = 0;
    __syncthreads();
    int e0 = bid * BIN_CHUNK;
    int e1 = min(E, e0 + BIN_CHUNK);
    int nv = (e1 - e0) >> 2;
    for (int i = tid; i < nv; i += BTB) {
        v4i d = nt_load4i(dst + e0 + (i << 2));
        atomicAdd(&hist[(unsigned)d.x >> 10], 1u);
        atomicAdd(&hist[(unsigned)d.y >> 10], 1u);
        atomicAdd(&hist[(unsigned)d.z >> 10], 1u);
        atomicAdd(&hist[(unsigned)d.w >> 10], 1u);
    }
    for (int e = e0 + (nv << 2) + tid; e < e1; e += BTB)
        atomicAdd(&hist[(unsigned)nt_load1i(dst + e) >> 10], 1u);
    __syncthreads();
    unsigned int* row = aux + (size_t)bid * NBUCK;
    for (int b = tid; b < NBUCK; b += BTB)
        row[b] = atomicAdd(&counts[b], hist[b]);   // old value = my base
}

// ---- exclusive prefix over bucket counts (single WG)
__global__ void k_scan(const unsigned int* __restrict__ counts,
                       unsigned int* __restrict__ bucket_base) {
    __shared__ unsigned int sc[512];
    int tid = threadIdx.x;
    unsigned int v = (tid < NBUCK) ? counts[tid] : 0u;
    sc[tid] = v;
    __syncthreads();
    for (int off = 1; off < 512; off <<= 1) {
        unsigned int t = (tid >= off) ? sc[tid - off] : 0u;
        __syncthreads();
        sc[tid] += t;
        __syncthreads();
    }
    if (tid <= NBUCK) bucket_base[tid] = sc[tid] - v;  // exclusive; [NBUCK]=E
}

// ---- P1b: scatter packed records (dstlocal<<22 | src) into bucket regions
__global__ __launch_bounds__(BTB) void k_bin_scatter(
        const int* __restrict__ src, const int* __restrict__ dst, int E,
        const unsigned int* __restrict__ bucket_base,
        const unsigned int* __restrict__ aux, unsigned int* __restrict__ rec) {
    __shared__ unsigned int cur[NBUCK];
    int tid = threadIdx.x, bid = blockIdx.x;
    const unsigned int* row = aux + (size_t)bid * NBUCK;
    for (int b = tid; b < NBUCK; b += BTB) cur[b] = bucket_base[b] + row[b];
    __syncthreads();
    int e0 = bid * BIN_CHUNK;
    int e1 = min(E, e0 + BIN_CHUNK);
    int nv = (e1 - e0) >> 2;
    for (int i = tid; i < nv; i += BTB) {
        v4i d = nt_load4i(dst + e0 + (i << 2));
        v4i s = nt_load4i(src + e0 + (i << 2));
        unsigned p0 = atomicAdd(&cur[(unsigned)d.x >> 10], 1u);
        unsigned p1 = atomicAdd(&cur[(unsigned)d.y >> 10], 1u);
        unsigned p2 = atomicAdd(&cur[(unsigned)d.z >> 10], 1u);
        unsigned p3 = atomicAdd(&cur[(unsigned)d.w >> 10], 1u);
        rec[p0] = (((unsigned)d.x & (NPB - 1u)) << 22) | (unsigned)s.x;
        rec[p1] = (((unsigned)d.y & (NPB - 1u)) << 22) | (unsigned)s.y;
        rec[p2] = (((unsigned)d.z & (NPB - 1u)) << 22) | (unsigned)s.z;
        rec[p3] = (((unsigned)d.w & (NPB - 1u)) << 22) | (unsigned)s.w;
    }
    for (int e = e0 + (nv << 2) + tid; e < e1; e += BTB) {
        unsigned d = (unsigned)nt_load1i(dst + e);
        unsigned p = atomicAdd(&cur[d >> 10], 1u);
        rec[p] = ((d & (NPB - 1u)) << 22) | (unsigned)nt_load1i(src + e);
    }
}

// ---- P2: per-bucket degree -> dis = rsqrt(deg+1), m1 = dis*x
__global__ __launch_bounds__(BTB) void k_deg_dis(
        const unsigned int* __restrict__ rec,
        const unsigned int* __restrict__ bucket_base,
        const float* __restrict__ x,
        float* __restrict__ dis, float* __restrict__ m1) {
    __shared__ unsigned int cnt[NPB];
    int tid = threadIdx.x, bid = blockIdx.x;
    for (int l = tid; l < NPB; l += BTB) cnt[l] = 0;
    __syncthreads();
    unsigned e0 = bucket_base[bid], e1 = bucket_base[bid + 1];
    unsigned ha = min((e0 + 3u) & ~3u, e1);          // aligned head end
    unsigned ta = (e1 & ~3u) > ha ? (e1 & ~3u) : ha; // aligned tail start
    if (e0 + tid < ha) atomicAdd(&cnt[nt_load1u(rec + e0 + tid) >> 22], 1u);
    for (unsigned i = (ha >> 2) + tid; i < (ta >> 2); i += BTB) {
        v4u r = nt_load4u(rec + (i << 2));
        atomicAdd(&cnt[r.x >> 22], 1u);
        atomicAdd(&cnt[r.y >> 22], 1u);
        atomicAdd(&cnt[r.z >> 22], 1u);
        atomicAdd(&cnt[r.w >> 22], 1u);
    }
    if (ta + tid < e1) atomicAdd(&cnt[nt_load1u(rec + ta + tid) >> 22], 1u);
    __syncthreads();
    int node0 = bid << 10;
    int nn = min(NPB, N_NODES - node0);
    for (int l = tid; l < nn; l += BTB) {
        int node = node0 + l;
        float r = rsqrtf((float)(cnt[l] + 1u));      // +1 self-loop; always > 0
        dis[node] = r;
        m1[node] = r * x[node];
    }
}

// ---- P3: layer-1 LDS aggregation + node MLP; writes h2m and out(self+bias)
__global__ __launch_bounds__(BTB) void k_layer1(
        const unsigned int* __restrict__ rec,
        const unsigned int* __restrict__ bucket_base,
        const float* __restrict__ dis, const float* __restrict__ m1,
        const float* __restrict__ W1, const float* __restrict__ b1,
        const float* __restrict__ W2, const float* __restrict__ b2,
        float2* __restrict__ h2m, float2* __restrict__ out) {
    __shared__ float acc[NPB];
    int tid = threadIdx.x, bid = blockIdx.x;
    for (int l = tid; l < NPB; l += BTB) acc[l] = 0.f;
    __syncthreads();
    unsigned e0 = bucket_base[bid], e1 = bucket_base[bid + 1];
    unsigned ha = min((e0 + 3u) & ~3u, e1);
    unsigned ta = (e1 & ~3u) > ha ? (e1 & ~3u) : ha;
    if (e0 + tid < ha) {
        unsigned r = nt_load1u(rec + e0 + tid);
        atomicAdd(&acc[r >> 22], m1[r & SRCMASK]);
    }
    for (unsigned i = (ha >> 2) + tid; i < (ta >> 2); i += BTB) {
        v4u r = nt_load4u(rec + (i << 2));
        float v0 = m1[r.x & SRCMASK];   // gathers: want these L2-resident
        float v1 = m1[r.y & SRCMASK];
        float v2 = m1[r.z & SRCMASK];
        float v3 = m1[r.w & SRCMASK];
        atomicAdd(&acc[r.x >> 22], v0);
        atomicAdd(&acc[r.y >> 22], v1);
        atomicAdd(&acc[r.z >> 22], v2);
        atomicAdd(&acc[r.w >> 22], v3);
    }
    if (ta + tid < e1) {
        unsigned r = nt_load1u(rec + ta + tid);
        atomicAdd(&acc[r >> 22], m1[r & SRCMASK]);
    }
    __syncthreads();
    int node0 = bid << 10;
    int nn = min(NPB, N_NODES - node0);
    float w1[8], bb1[8], w2[16];
    float bb20 = b2[0], bb21 = b2[1];
#pragma unroll
    for (int k = 0; k < 8; ++k) { w1[k] = W1[k]; bb1[k] = b1[k]; }
#pragma unroll
    for (int k = 0; k < 16; ++k) w2[k] = W2[k];
    for (int l = tid; l < nn; l += BTB) {
        int node = node0 + l;
        float d = dis[node];
        float s = d * (acc[l] + m1[node]);
        float a0 = 0.f, a1 = 0.f;
#pragma unroll
        for (int k = 0; k < 8; ++k) {
            float h = fmaxf(w1[k] * s + bb1[k], 0.f);
            a0 += h * w2[2 * k + 0];
            a1 += h * w2[2 * k + 1];
        }
        h2m[node] = make_float2(d * a0, d * a1);                    // dis[src]*h2
        out[node] = make_float2(bb20 + d * d * a0, bb21 + d * d * a1);
    }
}

// ---- P4: layer-2 LDS aggregation; out += dis[dst] * sum(h2m[src])
__global__ __launch_bounds__(BTB) void k_layer2(
        const unsigned int* __restrict__ rec,
        const unsigned int* __restrict__ bucket_base,
        const float* __restrict__ dis, const float2* __restrict__ h2m,
        float2* __restrict__ out) {
    __shared__ float ax[NPB];
    __shared__ float ay[NPB];
    int tid = threadIdx.x, bid = blockIdx.x;
    for (int l = tid; l < NPB; l += BTB) { ax[l] = 0.f; ay[l] = 0.f; }
    __syncthreads();
    unsigned e0 = bucket_base[bid], e1 = bucket_base[bid + 1];
    unsigned ha = min((e0 + 3u) & ~3u, e1);
    unsigned ta = (e1 & ~3u) > ha ? (e1 & ~3u) : ha;
    if (e0 + tid < ha) {
        unsigned r = nt_load1u(rec + e0 + tid);
        float2 v = h2m[r & SRCMASK];
        atomicAdd(&ax[r >> 22], v.x);
        atomicAdd(&ay[r >> 22], v.y);
    }
    for (unsigned i = (ha >> 2) + tid; i < (ta >> 2); i += BTB) {
        v4u r = nt_load4u(rec + (i << 2));
        float2 v0 = h2m[r.x & SRCMASK];   // gathers: want these L2-resident
        float2 v1 = h2m[r.y & SRCMASK];
        float2 v2 = h2m[r.z & SRCMASK];
        float2 v3 = h2m[r.w & SRCMASK];
        atomicAdd(&ax[r.x >> 22], v0.x);
        atomicAdd(&ay[r.x >> 22], v0.y);
        atomicAdd(&ax[r.y >> 22], v1.x);
        atomicAdd(&ay[r.y >> 22], v1.y);
        atomicAdd(&ax[r.z >> 22], v2.x);
        atomicAdd(&ay[r.z >> 22], v2.y);
        atomicAdd(&ax[r.w >> 22], v3.x);
        atomicAdd(&ay[r.w >> 22], v3.y);
    }
    if (ta + tid < e1) {
        unsigned r = nt_load1u(rec + ta + tid);
        float2 v = h2m[r & SRCMASK];
        atomicAdd(&ax[r >> 22], v.x);
        atomicAdd(&ay[r >> 22], v.y);
    }
    __syncthreads();
    int node0 = bid << 10;
    int nn = min(NPB, N_NODES - node0);
    for (int l = tid; l < nn; l += BTB) {
        int node = node0 + l;
        float d = dis[node];
        float2 o = out[node];
        out[node] = make_float2(o.x + d * ax[l], o.y + d * ay[l]);
    }
}

// ===========================================================================
// Fallback path (R1 kernels): global atomics — used only if ws too small.
// ===========================================================================
__global__ void k_count_deg(const int* __restrict__ dst, int E,
                            unsigned int* __restrict__ deg) {
    int i = blockIdx.x * blockDim.x + threadIdx.x;
    int stride = gridDim.x * blockDim.x;
    for (int e = i; e < E; e += stride) atomicAdd(&deg[dst[e]], 1u);
}
__global__ void k_dis_sinit(const unsigned int* __restrict__ deg,
                            const float* __restrict__ x,
                            float* __restrict__ dis, float* __restrict__ s, int N) {
    int i = blockIdx.x * blockDim.x + threadIdx.x;
    if (i < N) {
        float r = rsqrtf((float)(deg[i] + 1u));
        dis[i] = r;
        s[i] = r * r * x[i];
    }
}
__global__ void k_agg1(const int* __restrict__ src, const int* __restrict__ dst,
                       int E, const float* __restrict__ dis,
                       const float* __restrict__ x, float* __restrict__ s) {
    int i = blockIdx.x * blockDim.x + threadIdx.x;
    int stride = gridDim.x * blockDim.x;
    for (int e = i; e < E; e += stride) {
        int sj = src[e], dj = dst[e];
        atomicAdd(&s[dj], dis[sj] * dis[dj] * x[sj]);
    }
}
__global__ void k_node2(const float* __restrict__ s, const float* __restrict__ dis,
                        const float* __restrict__ W1, const float* __restrict__ b1,
                        const float* __restrict__ W2, const float* __restrict__ b2,
                        float2* __restrict__ h2, float2* __restrict__ out, int N) {
    int i = blockIdx.x * blockDim.x + threadIdx.x;
    if (i >= N) return;
    float si = s[i];
    float a0 = 0.f, a1 = 0.f;
#pragma unroll
    for (int k = 0; k < 8; ++k) {
        float hk = fmaxf(W1[k] * si + b1[k], 0.f);
        a0 += hk * W2[2 * k + 0];
        a1 += hk * W2[2 * k + 1];
    }
    h2[i] = make_float2(a0, a1);
    float r2 = dis[i] * dis[i];
    out[i] = make_float2(b2[0] + r2 * a0, b2[1] + r2 * a1);
}
__global__ void k_agg2(const int* __restrict__ src, const int* __restrict__ dst,
                       int E, const float* __restrict__ dis,
                       const float2* __restrict__ h2, float* __restrict__ out) {
    int i = blockIdx.x * blockDim.x + threadIdx.x;
    int stride = gridDim.x * blockDim.x;
    for (int e = i; e < E; e += stride) {
        int sj = src[e], dj = dst[e];
        float n = dis[sj] * dis[dj];
        float2 v = h2[sj];
        atomicAdd(&out[2 * dj + 0], n * v.x);
        atomicAdd(&out[2 * dj + 1], n * v.y);
    }
}

// ===========================================================================
extern "C" void kernel_launch(void* const* d_in, const int* in_sizes, int n_in,
                              void* d_out, int out_size, void* d_ws, size_t ws_size,
                              hipStream_t stream) {
    const float* x  = (const float*)d_in[0];
    const int*   ei = (const int*)d_in[1];   // [2, E] flat: src row, then dst row
    const float* W1 = (const float*)d_in[2];
    const float* b1 = (const float*)d_in[3];
    const float* W2 = (const float*)d_in[4];
    const float* b2 = (const float*)d_in[5];

    const int N = N_NODES;
    const int E = in_sizes[1] / 2;
    const int* src = ei;
    const int* dst = ei + E;
    float* out = (float*)d_out;

    const int nchunks = (E + BIN_CHUNK - 1) / BIN_CHUNK;

    // ---- workspace layout (fast path) ----
    char* ws = (char*)d_ws;
    size_t off_counts = 0;                                   // NBUCK u32
    size_t off_bb     = 4096;                                // NBUCK+1 u32
    size_t off_aux    = 8192;                                // nchunks*NBUCK u32
    size_t aux_bytes  = (size_t)nchunks * NBUCK * 4;
    size_t off_dis    = (off_aux + aux_bytes + 255) & ~(size_t)255;
    size_t off_m1     = off_dis + (size_t)N * 4;
    size_t off_h2m    = off_m1 + (size_t)N * 4;
    size_t off_rec    = off_h2m + (size_t)N * 8;
    size_t need       = off_rec + (size_t)E * 4 + 16;

    if (ws_size >= need) {
        unsigned int* counts = (unsigned int*)(ws + off_counts);
        unsigned int* bb     = (unsigned int*)(ws + off_bb);
        unsigned int* aux    = (unsigned int*)(ws + off_aux);
        float* dis           = (float*)(ws + off_dis);
        float* m1            = (float*)(ws + off_m1);
        float2* h2m          = (float2*)(ws + off_h2m);
        unsigned int* rec    = (unsigned int*)(ws + off_rec);

        hipMemsetAsync(counts, 0, NBUCK * sizeof(unsigned int), stream);
        k_bin_count<<<nchunks, BTB, 0, stream>>>(dst, E, counts, aux);
        k_scan<<<1, 512, 0, stream>>>(counts, bb);
        k_bin_scatter<<<nchunks, BTB, 0, stream>>>(src, dst, E, bb, aux, rec);
        k_deg_dis<<<NBUCK, BTB, 0, stream>>>(rec, bb, x, dis, m1);
        k_layer1<<<NBUCK, BTB, 0, stream>>>(rec, bb, dis, m1, W1, b1, W2, b2,
                                            h2m, (float2*)out);
        k_layer2<<<NBUCK, BTB, 0, stream>>>(rec, bb, dis, h2m, (float2*)out);
    } else {
        // fallback: R1 global-atomic path (needs 10 MB ws)
        unsigned int* deg = (unsigned int*)(ws);
        float* dis        = (float*)(ws + (size_t)N * 4);
        float* s          = (float*)(ws + (size_t)N * 8);
        float2* h2        = (float2*)(ws + (size_t)N * 12);
        hipMemsetAsync(deg, 0, (size_t)N * sizeof(unsigned int), stream);
        const int TB = 256;
        int nodeBlocks = (N + TB - 1) / TB;
        int edgeBlocks = (E + TB - 1) / TB;
        k_count_deg<<<edgeBlocks, TB, 0, stream>>>(dst, E, deg);
        k_dis_sinit<<<nodeBlocks, TB, 0, stream>>>(deg, x, dis, s, N);
        k_agg1<<<edgeBlocks, TB, 0, stream>>>(src, dst, E, dis, x, s);
        k_node2<<<nodeBlocks, TB, 0, stream>>>(s, dis, W1, b1, W2, b2, h2,
                                               (float2*)out, N);
        k_agg2<<<edgeBlocks, TB, 0, stream>>>(src, dst, E, dis, h2, out);
    }
}